// Round 8
// baseline (276.346 us; speedup 1.0000x reference)
//
#include <hip/hip_runtime.h>
#include <hip/hip_bf16.h>
#include <cstddef>
#include <cstdint>

typedef __attribute__((ext_vector_type(8))) short short8;
typedef __attribute__((ext_vector_type(16))) float float16;

#define C_CH 192
#define PK   9408      // C_CH * 49
#define D1   768
#define MAXCELLS 192   // LDS cell-cache capacity (192 * 384B = 72KB)

__device__ __forceinline__ ushort f2bf(float v) {
    return __builtin_bit_cast(unsigned short, __float2bfloat16(v));
}
__device__ __forceinline__ float bf2f(ushort u) {
    return __builtin_bit_cast(float, ((unsigned int)u) << 16);
}

// ---------------------------------------------------------------------------
// fp32 -> bf16 conversion for BOTH weight tensors in one launch
// ---------------------------------------------------------------------------
__global__ __launch_bounds__(256) void cvt_bf16_2(
    const float* __restrict__ in1, ushort* __restrict__ out1, int n4_1,
    const float* __restrict__ in2, ushort* __restrict__ out2, int n4_2)
{
    int i = blockIdx.x * 256 + threadIdx.x;
    const float* in; ushort* out;
    if (i < n4_1) { in = in1; out = out1; }
    else          { i -= n4_1; if (i >= n4_2) return; in = in2; out = out2; }
    float4 v = ((const float4*)in)[i];
    ushort4 o;
    o.x = f2bf(v.x); o.y = f2bf(v.y); o.z = f2bf(v.z); o.w = f2bf(v.w);
    ((ushort4*)out)[i] = o;
}

__global__ __launch_bounds__(256) void cvt_bf16(const float* __restrict__ in,
                                                ushort* __restrict__ out, int n4)
{
    int i = blockIdx.x * 256 + threadIdx.x;
    if (i >= n4) return;
    float4 v = ((const float4*)in)[i];
    ushort4 o;
    o.x = f2bf(v.x); o.y = f2bf(v.y); o.z = f2bf(v.z); o.w = f2bf(v.w);
    ((ushort4*)out)[i] = o;
}

// ---------------------------------------------------------------------------
// All 4 pyramid levels NCHW(fp32) -> NHWC(bf16), one launch.
// ---------------------------------------------------------------------------
__global__ __launch_bounds__(256) void nchw_to_nhwc(
    const float* __restrict__ f0, const float* __restrict__ f1,
    const float* __restrict__ f2, const float* __restrict__ f3,
    ushort* __restrict__ o0, ushort* __restrict__ o1,
    ushort* __restrict__ o2, ushort* __restrict__ o3)
{
    __shared__ float sm[C_CH][33];
    int t = blockIdx.x;
    int b = blockIdx.y;
    const float* in; ushort* out; int HW, hw0;
    if      (t < 512) { in = f0; out = o0; HW = 16384; hw0 = t * 32; }
    else if (t < 640) { in = f1; out = o1; HW = 4096;  hw0 = (t - 512) * 32; }
    else if (t < 672) { in = f2; out = o2; HW = 1024;  hw0 = (t - 640) * 32; }
    else              { in = f3; out = o3; HW = 256;   hw0 = (t - 672) * 32; }

    int tx = threadIdx.x & 31;
    int ty = threadIdx.x >> 5;    // 0..7

    const float* ip = in + (size_t)b * C_CH * HW + hw0;
    #pragma unroll
    for (int c = 0; c < C_CH; c += 8)
        sm[c + ty][tx] = ip[(size_t)(c + ty) * HW + tx];
    __syncthreads();

    ushort* op = out + ((size_t)b * HW + hw0) * C_CH;
    #pragma unroll
    for (int r0 = 0; r0 < 32; r0 += 8) {
        int r = r0 + ty;
        #pragma unroll
        for (int cc = 0; cc < 6; ++cc) {
            int c = cc * 32 + tx;
            op[(size_t)r * C_CH + c] = f2bf(sm[c][r]);
        }
    }
}

// ---------------------------------------------------------------------------
// RoIAlign gather, LDS cell-cache version. One block/RoI, 384 threads.
// The FPN level rule pins roi extent to ~6-11px -> tap footprint <= ~14x14
// cells. Stage unique cells into LDS once (each cell read once from L2/L3),
// taps then read LDS: ~4x traffic cut vs direct taps (301->~70MB device-wide).
// Oversized footprints (rare, extreme aspect) use the direct-global path.
// ---------------------------------------------------------------------------
__global__ __launch_bounds__(384) void roi_gather(
    const ushort* __restrict__ n0p, const ushort* __restrict__ n1p,
    const ushort* __restrict__ n2p, const ushort* __restrict__ n3p,
    const float* __restrict__ rois, ushort* __restrict__ pooled)
{
    __shared__ ushort s_cells[MAXCELLS * C_CH];   // 73728 B
    __shared__ ushort s_out[PK];                  // 18816 B
    __shared__ int2   s_ow[196][4];               // {byte-offset, weight-bits}

    const int n   = blockIdx.x;
    const int tid = threadIdx.x;

    float by1 = rois[n*5+0], bx1 = rois[n*5+1];
    float by2 = rois[n*5+2], bx2 = rois[n*5+3];
    int   b   = (int)rois[n*5+4];

    float hh = by2 - by1, ww = bx2 - bx1;
    int lvl = (int)rintf(4.0f + log2f(sqrtf(hh * ww)));
    lvl = min(max(lvl, 0), 3);

    const ushort* fm; int H;
    if      (lvl == 0) { fm = n0p; H = 128; }
    else if (lvl == 1) { fm = n1p; H = 64;  }
    else if (lvl == 2) { fm = n2p; H = 32;  }
    else               { fm = n3p; H = 16;  }
    float Hf = (float)H;

    float y1p = by1 * Hf, x1p = bx1 * Hf;
    float y2p = by2 * Hf, x2p = bx2 * Hf;
    float bin_h = fmaxf(y2p - y1p, 1.0f) * (1.0f / 7.0f);
    float bin_w = fmaxf(x2p - x1p, 1.0f) * (1.0f / 7.0f);

    // scalarized base pointer
    uintptr_t bp = (uintptr_t)(fm + (size_t)b * H * H * C_CH);
    unsigned int blo = __builtin_amdgcn_readfirstlane((unsigned int)bp);
    unsigned int bhi = __builtin_amdgcn_readfirstlane((unsigned int)(bp >> 32));
    const char* sbase = (const char*)((((uintptr_t)bhi) << 32) | blo);

    // footprint bounds: sample coords are monotone in grid index, so the
    // first (gy=0.25) and last (gy=6.75) samples bound the footprint.
    float yA = fminf(fmaxf(y1p + 0.25f * bin_h, 0.0f), Hf - 1.0f);
    float yB = fminf(fmaxf(y1p + 6.75f * bin_h, 0.0f), Hf - 1.0f);
    float xA = fminf(fmaxf(x1p + 0.25f * bin_w, 0.0f), Hf - 1.0f);
    float xB = fminf(fmaxf(x1p + 6.75f * bin_w, 0.0f), Hf - 1.0f);
    int y_lo = (int)floorf(yA);
    int y_hi = min((int)floorf(yB) + 1, H - 1);
    int x_lo = (int)floorf(xA);
    int x_hi = min((int)floorf(xB) + 1, H - 1);
    int ey = y_hi - y_lo + 1;
    int ex = x_hi - x_lo + 1;
    int cells = ey * ex;
    bool useLds = (cells <= MAXCELLS);   // block-uniform

    if (tid < 196) {
        int s  = tid;
        int sx = s & 1, sy = (s >> 1) & 1, ij = s >> 2;
        int i = ij / 7, j = ij - i * 7;

        float gy = (float)i + 0.25f + 0.5f * (float)sy;
        float y  = y1p + gy * bin_h;
        bool  vy = (y >= -1.0f) && (y <= Hf);
        float yc = fminf(fmaxf(y, 0.0f), Hf - 1.0f);
        int   y0 = (int)floorf(yc);
        float ly = yc - (float)y0;
        int   y1i = min(y0 + 1, H - 1);

        float gx = (float)j + 0.25f + 0.5f * (float)sx;
        float x  = x1p + gx * bin_w;
        bool  vx = (x >= -1.0f) && (x <= Hf);
        float xc = fminf(fmaxf(x, 0.0f), Hf - 1.0f);
        int   x0 = (int)floorf(xc);
        float lx = xc - (float)x0;
        int   x1i = min(x0 + 1, H - 1);

        float vm = (vy && vx) ? 0.25f : 0.0f;
        float w0 = (1.0f - ly) * (1.0f - lx) * vm;
        float w1 = (1.0f - ly) * lx * vm;
        float w2 = ly * (1.0f - lx) * vm;
        float w3 = ly * lx * vm;

        int o0, o1, o2, o3;
        if (useLds) {
            o0 = ((y0  - y_lo) * ex + (x0  - x_lo)) * (C_CH * 2);
            o1 = ((y0  - y_lo) * ex + (x1i - x_lo)) * (C_CH * 2);
            o2 = ((y1i - y_lo) * ex + (x0  - x_lo)) * (C_CH * 2);
            o3 = ((y1i - y_lo) * ex + (x1i - x_lo)) * (C_CH * 2);
        } else {
            o0 = (y0  * H + x0 ) * (C_CH * 2);
            o1 = (y0  * H + x1i) * (C_CH * 2);
            o2 = (y1i * H + x0 ) * (C_CH * 2);
            o3 = (y1i * H + x1i) * (C_CH * 2);
        }
        s_ow[s][0] = make_int2(o0, __builtin_bit_cast(int, w0));
        s_ow[s][1] = make_int2(o1, __builtin_bit_cast(int, w1));
        s_ow[s][2] = make_int2(o2, __builtin_bit_cast(int, w2));
        s_ow[s][3] = make_int2(o3, __builtin_bit_cast(int, w3));
    }

    if (useLds) {
        // stage footprint: cell row cy is ex*384B contiguous in NHWC memory
        int rowDw = ex * 96;              // dwords per cell row
        int totDw = cells * 96;
        const unsigned int* src = (const unsigned int*)sbase;
        unsigned int* dst = (unsigned int*)s_cells;
        int srcRow0 = (y_lo * H + x_lo) * 96;
        int rowStride = H * 96;
        for (int tix = tid; tix < totDw; tix += 384) {
            int cy = tix / rowDw;
            int d  = tix - cy * rowDw;
            dst[tix] = src[srcRow0 + cy * rowStride + d];
        }
    }
    __syncthreads();

    const int grp = tid / 96;            // 0..3 bin-group
    const int ci  = tid - grp * 96;      // channel-pair index
    const int c   = ci * 2;
    const int c4  = ci * 4;
    const int bin_lo = grp * 13;
    const int bin_hi = min(bin_lo + 13, 49);

    if (useLds) {
        for (int bin = bin_lo; bin < bin_hi; ++bin) {
            float a0 = 0.0f, a1 = 0.0f;
            #pragma unroll
            for (int sub = 0; sub < 4; ++sub) {
                int s = bin * 4 + sub;
                #pragma unroll
                for (int tp = 0; tp < 4; ++tp) {
                    int2 ow = s_ow[s][tp];
                    float w = __builtin_bit_cast(float, ow.y);
                    unsigned int u = *(const unsigned int*)((const char*)s_cells + ow.x + c4);
                    a0 = fmaf(__builtin_bit_cast(float, u << 16), w, a0);
                    a1 = fmaf(__builtin_bit_cast(float, u & 0xffff0000u), w, a1);
                }
            }
            s_out[(c + 0) * 49 + bin] = f2bf(a0);
            s_out[(c + 1) * 49 + bin] = f2bf(a1);
        }
    } else {
        for (int bin = bin_lo; bin < bin_hi; ++bin) {
            float a0 = 0.0f, a1 = 0.0f;
            #pragma unroll
            for (int sub = 0; sub < 4; ++sub) {
                int s = bin * 4 + sub;
                #pragma unroll
                for (int tp = 0; tp < 4; ++tp) {
                    int2 ow = s_ow[s][tp];
                    float w = __builtin_bit_cast(float, ow.y);
                    unsigned int u = *(const unsigned int*)(sbase + ow.x + c4);
                    a0 = fmaf(__builtin_bit_cast(float, u << 16), w, a0);
                    a1 = fmaf(__builtin_bit_cast(float, u & 0xffff0000u), w, a1);
                }
            }
            s_out[(c + 0) * 49 + bin] = f2bf(a0);
            s_out[(c + 1) * 49 + bin] = f2bf(a1);
        }
    }
    __syncthreads();

    unsigned int* po = (unsigned int*)(pooled + (size_t)n * PK);
    const unsigned int* so = (const unsigned int*)s_out;
    for (int idx = tid; idx < PK / 2; idx += 384) po[idx] = so[idx];
}

// ---------------------------------------------------------------------------
// RoIAlign from NCHW fp32 (fallback path, proven): 1 thread / output element
// ---------------------------------------------------------------------------
__global__ __launch_bounds__(256) void roi_align_nchw(
    const float* __restrict__ f0, const float* __restrict__ f1,
    const float* __restrict__ f2, const float* __restrict__ f3,
    const float* __restrict__ rois, ushort* __restrict__ pooled, int n_rois)
{
    int idx = blockIdx.x * 256 + threadIdx.x;
    if (idx >= n_rois * PK) return;
    int n  = idx / PK;
    int r  = idx - n * PK;
    int c  = r / 49;
    int ij = r - c * 49;
    int i  = ij / 7;
    int j  = ij - i * 7;

    float by1 = rois[n*5+0], bx1 = rois[n*5+1];
    float by2 = rois[n*5+2], bx2 = rois[n*5+3];
    int   b   = (int)rois[n*5+4];

    float hh = by2 - by1, ww = bx2 - bx1;
    int lvl = (int)rintf(4.0f + log2f(sqrtf(hh * ww)));
    lvl = min(max(lvl, 0), 3);

    const float* fmap; int H;
    if      (lvl == 0) { fmap = f0; H = 128; }
    else if (lvl == 1) { fmap = f1; H = 64;  }
    else if (lvl == 2) { fmap = f2; H = 32;  }
    else               { fmap = f3; H = 16;  }
    float Hf = (float)H;

    float y1p = by1 * Hf, x1p = bx1 * Hf;
    float bin_h = fmaxf(by2 * Hf - y1p, 1.0f) * (1.0f / 7.0f);
    float bin_w = fmaxf(bx2 * Hf - x1p, 1.0f) * (1.0f / 7.0f);

    const float* base = fmap + ((size_t)b * C_CH + c) * (size_t)(H * H);

    float acc = 0.0f;
    #pragma unroll
    for (int sy = 0; sy < 2; ++sy) {
        float y  = y1p + ((float)i + 0.25f + 0.5f * (float)sy) * bin_h;
        bool  vy = (y >= -1.0f) && (y <= Hf);
        float yc = fminf(fmaxf(y, 0.0f), Hf - 1.0f);
        int   y0 = (int)floorf(yc);
        float ly = yc - (float)y0;
        int   y1i = min(y0 + 1, H - 1);
        #pragma unroll
        for (int sx = 0; sx < 2; ++sx) {
            float x  = x1p + ((float)j + 0.25f + 0.5f * (float)sx) * bin_w;
            bool  vx = (x >= -1.0f) && (x <= Hf);
            float xc = fminf(fmaxf(x, 0.0f), Hf - 1.0f);
            int   x0 = (int)floorf(xc);
            float lx = xc - (float)x0;
            int   x1i = min(x0 + 1, H - 1);
            if (vy && vx) {
                float v = base[y0 * H + x0 ] * (1.0f - ly) * (1.0f - lx)
                        + base[y0 * H + x1i] * (1.0f - ly) * lx
                        + base[y1i * H + x0 ] * ly * (1.0f - lx)
                        + base[y1i * H + x1i] * ly * lx;
                acc += v;
            }
        }
    }
    pooled[idx] = f2bf(acc * 0.25f);
}

// ---------------------------------------------------------------------------
// bf16 MFMA GEMM, 64x64 tile (FC2 + fallback). MODE 0: fp32 out bias+relu.
// MODE 1: bf16 out bias+relu. MODE 2: fp32 partial, ragged split-K.
// ---------------------------------------------------------------------------
template<int MODE>
__global__ __launch_bounds__(256) void mfma_gemm(
    const ushort* __restrict__ A, const ushort* __restrict__ W,
    const float* __restrict__ bias, void* __restrict__ outp,
    int M, int N, int K, int nkPer, int nkTotal)
{
    __shared__ char ldsA[2][8192];
    __shared__ char ldsB[2][8192];

    const int t    = threadIdx.x;
    const int lane = t & 63;
    const int wave = t >> 6;
    const int wm = wave >> 1, wn = wave & 1;

    const int m0 = blockIdx.y * 64;
    const int n0 = blockIdx.x * 64;
    const int kb = (MODE == 2) ? blockIdx.z * nkPer : 0;
    const int nk = (MODE == 2) ? min(nkPer, nkTotal - kb) : nkPer;

    const int ks   = t & 3;
    const int mrow = t >> 2;
    const int g    = mrow >> 5;
    const int rw   = mrow & 31;
    const int lof0 = ks*2048 + g*1024 + ((     rw) ^ (ks<<2))*16;
    const int lof1 = ks*2048 + g*1024 + ((32 + rw) ^ (ks<<2))*16;

    const int arow = min(m0 + mrow, M-1);
    const int brow = n0 + mrow;
    const ushort* ap = A + (size_t)arow * K + (size_t)kb * 64 + ks*16;
    const ushort* bp = W + (size_t)brow * K + (size_t)kb * 64 + ks*16;

    float4 ra0, ra1, rb0, rb1;
    float4 qa0, qa1, qb0, qb1;

    ra0 = ((const float4*)ap)[0]; ra1 = ((const float4*)ap)[1];
    rb0 = ((const float4*)bp)[0]; rb1 = ((const float4*)bp)[1];
    *(float4*)&ldsA[0][lof0] = ra0; *(float4*)&ldsA[0][lof1] = ra1;
    *(float4*)&ldsB[0][lof0] = rb0; *(float4*)&ldsB[0][lof1] = rb1;
    {
        int k1 = min(1, nk - 1);
        const ushort* ap1 = ap + (size_t)k1 * 64;
        const ushort* bp1 = bp + (size_t)k1 * 64;
        ra0 = ((const float4*)ap1)[0]; ra1 = ((const float4*)ap1)[1];
        rb0 = ((const float4*)bp1)[0]; rb1 = ((const float4*)bp1)[1];
    }
    __syncthreads();

    float16 acc = {};

    for (int kt = 0; kt < nk; ++kt) {
        {
            int k2 = min(kt + 2, nk - 1);
            const ushort* ap2 = ap + (size_t)k2 * 64;
            const ushort* bp2 = bp + (size_t)k2 * 64;
            qa0 = ((const float4*)ap2)[0]; qa1 = ((const float4*)ap2)[1];
            qb0 = ((const float4*)bp2)[0]; qb1 = ((const float4*)bp2)[1];
        }
        if (kt + 1 < nk) {
            char* dA = ldsA[(kt+1)&1]; char* dB = ldsB[(kt+1)&1];
            *(float4*)&dA[lof0] = ra0; *(float4*)&dA[lof1] = ra1;
            *(float4*)&dB[lof0] = rb0; *(float4*)&dB[lof1] = rb1;
        }
        const char* sA = ldsA[kt&1]; const char* sB = ldsB[kt&1];
        #pragma unroll
        for (int s = 0; s < 4; ++s) {
            int ro = s*2048 + (lane ^ (s<<2))*16;
            short8 af = *(const short8*)&sA[wm*1024 + ro];
            short8 bf = *(const short8*)&sB[wn*1024 + ro];
            acc = __builtin_amdgcn_mfma_f32_32x32x16_bf16(af, bf, acc, 0, 0, 0);
        }
        __syncthreads();
        ra0 = qa0; ra1 = qa1; rb0 = qb0; rb1 = qb1;
    }

    const int col   = lane & 31;
    const int rbase = 4 * (lane >> 5);
    const int nG    = n0 + wn*32 + col;

    if (MODE == 2) {
        float* O = (float*)outp + (size_t)blockIdx.z * M * N;
        #pragma unroll
        for (int r = 0; r < 16; ++r) {
            int row = (r & 3) + 8*(r >> 2) + rbase;
            int mG  = m0 + wm*32 + row;
            if (mG < M) O[(size_t)mG * N + nG] = acc[r];
        }
    } else if (MODE == 1) {
        const float bv = bias[nG];
        ushort* O = (ushort*)outp;
        #pragma unroll
        for (int r = 0; r < 16; ++r) {
            int row = (r & 3) + 8*(r >> 2) + rbase;
            int mG  = m0 + wm*32 + row;
            if (mG < M) O[(size_t)mG * N + nG] = f2bf(fmaxf(acc[r] + bv, 0.0f));
        }
    } else {
        const float bv = bias[nG];
        float* O = (float*)outp;
        #pragma unroll
        for (int r = 0; r < 16; ++r) {
            int row = (r & 3) + 8*(r >> 2) + rbase;
            int mG  = m0 + wm*32 + row;
            if (mG < M) O[(size_t)mG * N + nG] = fmaxf(acc[r] + bv, 0.0f);
        }
    }
}

// ---------------------------------------------------------------------------
// FC1 GEMM: 64(M) x 128(N) tile, BK=64, ragged split-K, fp32 partials.
// 4 waves as 2x2; each wave = 32 rows x 64 cols (2 MFMA col-tiles).
// A traffic x6, B traffic x8 (vs x12/x16 at 64x64). LDS 48KB -> 2 blocks/CU.
// ---------------------------------------------------------------------------
__global__ __launch_bounds__(256) void mfma_gemm_fc1(
    const ushort* __restrict__ A, const ushort* __restrict__ W,
    float* __restrict__ P, int M, int N, int K, int nkPer, int nkTotal)
{
    __shared__ char ldsA[2][8192];
    __shared__ char ldsB[2][16384];

    const int t    = threadIdx.x;
    const int lane = t & 63;
    const int wave = t >> 6;
    const int wm = wave >> 1, wn = wave & 1;

    const int m0 = blockIdx.y * 64;
    const int n0 = blockIdx.x * 128;
    const int kb = blockIdx.z * nkPer;
    const int nk = min(nkPer, nkTotal - kb);

    const int ks   = t & 3;
    const int mrow = t >> 2;          // 0..63
    const int g0   = mrow >> 5;       // 0..1
    const int rw   = mrow & 31;
    const int swz  = ks << 2;
    const int slot = (rw ^ swz) * 16;
    const int lofA  = ks*2048 + g0*1024 + slot;        // h1 at +512
    const int lofB0 = ks*4096 + g0*1024 + slot;        // rows 0..63
    const int lofB1 = ks*4096 + (g0+2)*1024 + slot;    // rows 64..127

    const int arow = min(m0 + mrow, M-1);
    const ushort* ap  = A + (size_t)arow * K + (size_t)kb * 64 + ks*16;
    const ushort* bp0 = W + (size_t)(n0 + mrow)      * K + (size_t)kb * 64 + ks*16;
    const ushort* bp1 = W + (size_t)(n0 + mrow + 64) * K + (size_t)kb * 64 + ks*16;

    float4 ra0, ra1, rb00, rb01, rb10, rb11;
    float4 qa0, qa1, qb00, qb01, qb10, qb11;

    ra0  = ((const float4*)ap)[0];  ra1  = ((const float4*)ap)[1];
    rb00 = ((const float4*)bp0)[0]; rb01 = ((const float4*)bp0)[1];
    rb10 = ((const float4*)bp1)[0]; rb11 = ((const float4*)bp1)[1];
    *(float4*)&ldsA[0][lofA]        = ra0;  *(float4*)&ldsA[0][lofA + 512]  = ra1;
    *(float4*)&ldsB[0][lofB0]       = rb00; *(float4*)&ldsB[0][lofB0 + 512] = rb01;
    *(float4*)&ldsB[0][lofB1]       = rb10; *(float4*)&ldsB[0][lofB1 + 512] = rb11;
    {
        int k1 = min(1, nk - 1);
        size_t o = (size_t)k1 * 64;
        ra0  = ((const float4*)(ap  + o))[0]; ra1  = ((const float4*)(ap  + o))[1];
        rb00 = ((const float4*)(bp0 + o))[0]; rb01 = ((const float4*)(bp0 + o))[1];
        rb10 = ((const float4*)(bp1 + o))[0]; rb11 = ((const float4*)(bp1 + o))[1];
    }
    __syncthreads();

    float16 acc0 = {}, acc1 = {};

    for (int kt = 0; kt < nk; ++kt) {
        {
            int k2 = min(kt + 2, nk - 1);
            size_t o = (size_t)k2 * 64;
            qa0  = ((const float4*)(ap  + o))[0]; qa1  = ((const float4*)(ap  + o))[1];
            qb00 = ((const float4*)(bp0 + o))[0]; qb01 = ((const float4*)(bp0 + o))[1];
            qb10 = ((const float4*)(bp1 + o))[0]; qb11 = ((const float4*)(bp1 + o))[1];
        }
        if (kt + 1 < nk) {
            char* dA = ldsA[(kt+1)&1]; char* dB = ldsB[(kt+1)&1];
            *(float4*)&dA[lofA]        = ra0;  *(float4*)&dA[lofA + 512]  = ra1;
            *(float4*)&dB[lofB0]       = rb00; *(float4*)&dB[lofB0 + 512] = rb01;
            *(float4*)&dB[lofB1]       = rb10; *(float4*)&dB[lofB1 + 512] = rb11;
        }
        const char* sA = ldsA[kt&1]; const char* sB = ldsB[kt&1];
        #pragma unroll
        for (int s = 0; s < 4; ++s) {
            int sl = (lane ^ (s<<2)) * 16;
            short8 af = *(const short8*)&sA[s*2048 + wm*1024 + sl];
            short8 b0 = *(const short8*)&sB[s*4096 + (wn*2 + 0)*1024 + sl];
            short8 b1 = *(const short8*)&sB[s*4096 + (wn*2 + 1)*1024 + sl];
            acc0 = __builtin_amdgcn_mfma_f32_32x32x16_bf16(af, b0, acc0, 0, 0, 0);
            acc1 = __builtin_amdgcn_mfma_f32_32x32x16_bf16(af, b1, acc1, 0, 0, 0);
        }
        __syncthreads();
        ra0 = qa0; ra1 = qa1;
        rb00 = qb00; rb01 = qb01; rb10 = qb10; rb11 = qb11;
    }

    float* O = P + (size_t)blockIdx.z * M * N;
    const int col   = lane & 31;
    const int rbase = 4 * (lane >> 5);
    #pragma unroll
    for (int r = 0; r < 16; ++r) {
        int row = (r & 3) + 8*(r >> 2) + rbase;
        int mG  = m0 + wm*32 + row;
        if (mG < M) {
            int nG = n0 + wn*64 + col;
            O[(size_t)mG * N + nG]      = acc0[r];
            O[(size_t)mG * N + nG + 32] = acc1[r];
        }
    }
}

// ---------------------------------------------------------------------------
// FC1 split-K reduce -> bf16 Y
// ---------------------------------------------------------------------------
__global__ __launch_bounds__(256) void reduce_relu_bf16(
    const float* __restrict__ P, const float* __restrict__ bias,
    ushort* __restrict__ Y, int MN, int N, int S)
{
    int idx = blockIdx.x * 256 + threadIdx.x;
    if (idx >= MN / 4) return;
    float4 s = ((const float4*)P)[idx];
    for (int k = 1; k < S; ++k) {
        float4 p = ((const float4*)(P + (size_t)k * MN))[idx];
        s.x += p.x; s.y += p.y; s.z += p.z; s.w += p.w;
    }
    int n4 = idx % (N / 4);
    float4 bv = ((const float4*)bias)[n4];
    ushort4 o;
    o.x = f2bf(fmaxf(s.x + bv.x, 0.0f));
    o.y = f2bf(fmaxf(s.y + bv.y, 0.0f));
    o.z = f2bf(fmaxf(s.z + bv.z, 0.0f));
    o.w = f2bf(fmaxf(s.w + bv.w, 0.0f));
    ((ushort4*)Y)[idx] = o;
}

// ---------------------------------------------------------------------------
// Fused FC2-reduce + relu + heads. One block per RoI (256 threads).
// ---------------------------------------------------------------------------
__global__ __launch_bounds__(256) void reduce_heads(
    const float* __restrict__ P2, const float* __restrict__ b2, int S, int MN,
    const float* __restrict__ w_bbox, const float* __restrict__ b_bbox,
    const float* __restrict__ w_cls,  const float* __restrict__ b_cls,
    const float* __restrict__ w_reg,  const float* __restrict__ b_reg,
    const float* __restrict__ w_unc,  const float* __restrict__ b_unc,
    float* __restrict__ out, int n_rois)
{
    __shared__ float zrow[D1];
    const int m   = blockIdx.x;
    const int tid = threadIdx.x;

    const float* Pm = P2 + (size_t)m * D1;
    #pragma unroll
    for (int r = 0; r < 3; ++r) {               // 768 = 3 * 256
        int k = r * 256 + tid;
        float v = Pm[k];
        for (int s = 1; s < S; ++s) v += Pm[(size_t)s * MN + k];
        zrow[k] = fmaxf(v + b2[k], 0.0f);
    }
    __syncthreads();

    const int wave = tid >> 6;
    const int lane = tid & 63;
    for (int o = wave; o < 14; o += 4) {
        const float* w; float bb;
        if      (o < 8)  { w = w_bbox + o * D1;        bb = b_bbox[o]; }
        else if (o < 10) { w = w_cls  + (o - 8) * D1;  bb = b_cls[o - 8]; }
        else if (o < 12) { w = w_reg  + (o - 10) * D1; bb = b_reg[o - 10]; }
        else             { w = w_unc  + (o - 12) * D1; bb = b_unc[o - 12]; }
        float p = 0.0f;
        #pragma unroll
        for (int r = 0; r < 12; ++r) {          // 768 = 12 * 64
            int k = r * 64 + lane;
            p = fmaf(zrow[k], w[k], p);
        }
        #pragma unroll
        for (int d = 32; d >= 1; d >>= 1) p += __shfl_down(p, d, 64);
        if (lane == 0) {
            int off;
            int clsOff = n_rois * 8;
            int regOff = n_rois * 10;
            if      (o < 8)  off = m * 8 + o;
            else if (o < 10) off = clsOff + m * 2 + (o - 8);
            else if (o < 12) off = regOff + m * 4 + (o - 10) * 2;
            else             off = regOff + m * 4 + (o - 12) * 2 + 1;
            out[off] = p + bb;
        }
    }
}

// ---------------------------------------------------------------------------
// Heads (fallback path)
// ---------------------------------------------------------------------------
__global__ __launch_bounds__(256) void heads_kernel(
    const float* __restrict__ Z,
    const float* __restrict__ w_bbox, const float* __restrict__ b_bbox,
    const float* __restrict__ w_cls,  const float* __restrict__ b_cls,
    const float* __restrict__ w_reg,  const float* __restrict__ b_reg,
    const float* __restrict__ w_unc,  const float* __restrict__ b_unc,
    float* __restrict__ out, int n_rois)
{
    int idx = blockIdx.x * 256 + threadIdx.x;
    if (idx >= n_rois * 14) return;
    int n = idx / 14;
    int o = idx - n * 14;

    const float* w; float bb;
    if      (o < 8)  { w = w_bbox + o * D1;        bb = b_bbox[o]; }
    else if (o < 10) { w = w_cls  + (o - 8) * D1;  bb = b_cls[o - 8]; }
    else if (o < 12) { w = w_reg  + (o - 10) * D1; bb = b_reg[o - 10]; }
    else             { w = w_unc  + (o - 12) * D1; bb = b_unc[o - 12]; }

    const float* z = Z + (size_t)n * D1;
    float s = bb;
    for (int k = 0; k < D1; k += 4) {
        float4 zv = *(const float4*)(z + k);
        float4 wv = *(const float4*)(w + k);
        s = fmaf(zv.x, wv.x, s);
        s = fmaf(zv.y, wv.y, s);
        s = fmaf(zv.z, wv.z, s);
        s = fmaf(zv.w, wv.w, s);
    }

    int off;
    int clsOff = n_rois * 8;
    int regOff = n_rois * 10;
    if      (o < 8)  off = n * 8 + o;
    else if (o < 10) off = clsOff + n * 2 + (o - 8);
    else if (o < 12) off = regOff + n * 4 + (o - 10) * 2;
    else             off = regOff + n * 4 + (o - 12) * 2 + 1;
    out[off] = s;
}

// ---------------------------------------------------------------------------
extern "C" void kernel_launch(void* const* d_in, const int* in_sizes, int n_in,
                              void* d_out, int out_size, void* d_ws, size_t ws_size,
                              hipStream_t stream)
{
    const float* f0   = (const float*)d_in[0];
    const float* f1   = (const float*)d_in[1];
    const float* f2   = (const float*)d_in[2];
    const float* f3   = (const float*)d_in[3];
    const float* rois = (const float*)d_in[4];
    const float* w1   = (const float*)d_in[5];
    const float* b1   = (const float*)d_in[6];
    const float* w2   = (const float*)d_in[7];
    const float* b2   = (const float*)d_in[8];
    const float* w_bbox = (const float*)d_in[9];
    const float* b_bbox = (const float*)d_in[10];
    const float* w_cls  = (const float*)d_in[11];
    const float* b_cls  = (const float*)d_in[12];
    const float* w_reg  = (const float*)d_in[13];
    const float* b_reg  = (const float*)d_in[14];
    const float* w_unc  = (const float*)d_in[15];
    const float* b_unc  = (const float*)d_in[16];
    float* out = (float*)d_out;

    const int n_rois = in_sizes[4] / 5;                  // 1000
    const int B      = in_sizes[0] / (C_CH * 128 * 128); // 4

    const size_t nh0B = (size_t)B * 16384 * C_CH * 2;
    const size_t nh1B = (size_t)B * 4096  * C_CH * 2;
    const size_t nh2B = (size_t)B * 1024  * C_CH * 2;
    const size_t nh3B = (size_t)B * 256   * C_CH * 2;
    const size_t nhAll = nh0B + nh1B + nh2B + nh3B;      // 33.4 MB
    const size_t poolB = (size_t)n_rois * PK * 2;        // 18.8 MB
    const size_t w1Bb  = (size_t)D1 * PK * 2;            // 14.45 MB
    const size_t w2Bb  = (size_t)D1 * D1 * 2;
    const size_t Yb    = (size_t)n_rois * D1 * 2;
    const size_t Zb    = (size_t)n_rois * D1 * 4;

    const int SPLIT1 = 5;   // FC1: 30,30,30,30,27 of 147 BK-iters
    const int SPLIT2 = 2;   // FC2: 6+6
    const size_t Pb  = (size_t)SPLIT1 * n_rois * D1 * 4; // 15.36 MB
    const size_t P2b = (size_t)SPLIT2 * n_rois * D1 * 4; // 6.14 MB

    const size_t needFlat = nhAll + poolB + w1Bb + w2Bb + Yb + Pb + P2b; // ~91 MB
    const size_t needX    = nhAll + poolB + w2Bb + Yb + Zb;              // ~58 MB

    char* ws = (char*)d_ws;

    if (ws_size >= needFlat || ws_size >= needX) {
        const bool flat = (ws_size >= needFlat);

        ushort* nh0 = (ushort*)ws;
        ushort* nh1 = nh0 + nh0B/2;
        ushort* nh2 = nh1 + nh1B/2;
        ushort* nh3 = nh2 + nh2B/2;
        ushort* pooledB = (ushort*)(ws + nhAll);
        ushort* w2B = (ushort*)(ws + nhAll + poolB);
        ushort* Y   = w2B + w2Bb/2;

        ushort* w1B; float *P, *P2;
        if (flat) {
            char* p = (char*)Y + Yb;
            w1B = (ushort*)p;          p += w1Bb;
            P   = (float*)p;           p += Pb;
            P2  = (float*)p;
        } else {
            // aliased Plan X (proven r6/r7): w1B + P overlay dead nhwc region
            w1B = (ushort*)ws;
            P   = (float*)(ws + w1Bb);          // 14.45 + 15.36 <= 33.4 ✓
            P2  = (float*)ws;                    // after FC1 gemm, w1B/P dead? no:
            // P2 written by FC2 gemm (after FC1 reduce); w1B dead then ✓
        }

        nchw_to_nhwc<<<dim3(680, B), 256, 0, stream>>>(f0, f1, f2, f3,
                                                       nh0, nh1, nh2, nh3);
        roi_gather<<<n_rois, 384, 0, stream>>>(nh0, nh1, nh2, nh3, rois, pooledB);

        {
            int n41 = D1*PK/4, n42 = D1*D1/4;
            cvt_bf16_2<<<(n41 + n42 + 255)/256, 256, 0, stream>>>(
                w1, w1B, n41, w2, w2B, n42);
        }
        // FC1: 64x128 split-K partials + reduce -> Y bf16
        {
            int nkTotal = PK / 64;                          // 147
            int nkPer   = (nkTotal + SPLIT1 - 1) / SPLIT1;  // 30
            dim3 grid(D1/128, (n_rois + 63)/64, SPLIT1);    // 6 x 16 x 5
            mfma_gemm_fc1<<<grid, 256, 0, stream>>>(pooledB, w1B, P,
                                                    n_rois, D1, PK, nkPer, nkTotal);
            int MN = n_rois * D1;
            reduce_relu_bf16<<<(MN/4 + 255)/256, 256, 0, stream>>>(P, b1, Y, MN, D1, SPLIT1);
        }
        // FC2 partials -> fused reduce+relu+heads
        {
            int nkTotal = D1 / 64;                          // 12
            int nkPer   = nkTotal / SPLIT2;                 // 6
            dim3 grid(D1/64, (n_rois + 63)/64, SPLIT2);
            mfma_gemm<2><<<grid, 256, 0, stream>>>(Y, w2B, nullptr, P2,
                                                   n_rois, D1, D1, nkPer, nkTotal);
            int MN = n_rois * D1;
            reduce_heads<<<n_rois, 256, 0, stream>>>(P2, b2, SPLIT2, MN,
                w_bbox, b_bbox, w_cls, b_cls, w_reg, b_reg, w_unc, b_unc, out, n_rois);
        }
    } else {
        // ------- fallback: proven 39.1 MB layout -------
        ushort* pooledB = (ushort*)ws;
        ushort* w1B = pooledB + poolB/2;
        ushort* w2B = w1B + w1Bb/2;
        ushort* Y   = w2B + w2Bb/2;
        float*  Z   = (float*)((char*)Y + Yb);

        cvt_bf16<<<((D1*PK/4) + 255)/256, 256, 0, stream>>>(w1, w1B, D1*PK/4);
        cvt_bf16<<<((D1*D1/4) + 255)/256, 256, 0, stream>>>(w2, w2B, D1*D1/4);
        {
            int total = n_rois * PK;
            roi_align_nchw<<<(total + 255)/256, 256, 0, stream>>>(
                f0, f1, f2, f3, rois, pooledB, n_rois);
        }
        {
            dim3 grid(D1/64, (n_rois + 63)/64);
            mfma_gemm<1><<<grid, 256, 0, stream>>>(pooledB, w1B, b1, Y,
                                                   n_rois, D1, PK, PK/64, PK/64);
        }
        {
            dim3 grid(D1/64, (n_rois + 63)/64);
            mfma_gemm<0><<<grid, 256, 0, stream>>>(Y, w2B, b2, Z,
                                                   n_rois, D1, D1, D1/64, D1/64);
        }
        heads_kernel<<<(n_rois*14 + 255)/256, 256, 0, stream>>>(
            Z, w_bbox, b_bbox, w_cls, b_cls, w_reg, b_reg, w_unc, b_unc, out, n_rois);
    }
}